// Round 1
// 2198.459 us; speedup vs baseline: 1.1383x; 1.1383x over previous
//
#include <hip/hip_runtime.h>
#include <hip/hip_bf16.h>
#include <math.h>

#define BB 2
#define TT 1024
#define VV 32000
#define EE 768
#define HH 12
#define LL 4
#define HDIM 64
#define BT (BB*TT)   // 2048
#define E3 (3*EE)    // 2304
#define NBLOG (VV/128)  // 250 n-blocks in logits GEMM

typedef __hip_bfloat16 bf16;
typedef __attribute__((ext_vector_type(8))) short bf16x8;
typedef __attribute__((ext_vector_type(4))) float f32x4;

__device__ __forceinline__ float bf2f(bf16 v) { return __bfloat162float(v); }
__device__ __forceinline__ bf16 f2bf(float v) { return __float2bfloat16(v); }

__device__ __forceinline__ void async_load16(const void* g, void* l) {
  __builtin_amdgcn_global_load_lds((const __attribute__((address_space(1))) void*)g,
                                   (__attribute__((address_space(3))) void*)l, 16, 0, 0);
}

__device__ __forceinline__ float gelu_tanh(float x) {
  float u = 0.7978845608028654f * (x + 0.044715f * x * x * x);
  return 0.5f * x * (1.0f + tanhf(u));
}

// ---------------- dtype detect + conversion ----------------

__global__ void detect_kernel(const unsigned* __restrict__ raw, int* flag, int force_bf16) {
  if (force_bf16) { *flag = 0; return; }
  *flag = (raw[0] == 0x3F800000u && raw[1] == 0x3F800000u) ? 1 : 0;
}

__global__ __launch_bounds__(256) void convert_kernel(const void* __restrict__ in,
                                                      bf16* __restrict__ out, long n,
                                                      const int* __restrict__ flag) {
  long i = (long)blockIdx.x * 256 + threadIdx.x;
  if (i >= n) return;
  int f = *flag;
  out[i] = f ? f2bf(((const float*)in)[i]) : ((const bf16*)in)[i];
}

__global__ void zero_loss_kernel(float* p) { *p = 0.f; }

__global__ void write_loss_kernel(const float* p, void* out, const int* flag) {
  if (*flag) ((float*)out)[(size_t)BT * VV] = *p;
  else       ((bf16*)out)[(size_t)BT * VV] = f2bf(*p);
}

// one layer of a (L,R,C) tensor -> (C,R) bf16
__global__ __launch_bounds__(256) void transpose_kernel(const void* __restrict__ in,
                                                        bf16* __restrict__ out,
                                                        int R, int C, int layer,
                                                        const int* __restrict__ flag) {
  __shared__ bf16 tile[32][33];
  int f = *flag;
  const float* inf = (const float*)in + (size_t)layer * R * C;
  const bf16* inb  = (const bf16*)in  + (size_t)layer * R * C;
  int r0 = blockIdx.y * 32, c0 = blockIdx.x * 32;
#pragma unroll
  for (int i = 0; i < 4; ++i) {
    size_t idx = (size_t)(r0 + threadIdx.y + i * 8) * C + c0 + threadIdx.x;
    tile[threadIdx.y + i * 8][threadIdx.x] = f ? f2bf(inf[idx]) : inb[idx];
  }
  __syncthreads();
#pragma unroll
  for (int i = 0; i < 4; ++i) {
    int c = c0 + threadIdx.y + i * 8;
    out[(size_t)c * R + r0 + threadIdx.x] = tile[threadIdx.x][threadIdx.y + i * 8];
  }
}

// ---------------- model kernels (all consume bf16 copies) ----------------

__global__ __launch_bounds__(256) void embed_kernel(const int* __restrict__ tok,
                                                    const bf16* __restrict__ wte,
                                                    const bf16* __restrict__ wpe,
                                                    float* __restrict__ x) {
  int r = blockIdx.x;
  int tk = tok[r];
  int t = r & (TT - 1);
#pragma unroll
  for (int i = 0; i < 3; ++i) {
    int e = threadIdx.x + i * 256;
    x[(size_t)r * EE + e] = bf2f(wte[(size_t)tk * EE + e]) + bf2f(wpe[(size_t)t * EE + e]);
  }
}

__global__ __launch_bounds__(256) void ln_kernel(const float* __restrict__ x,
                                                 const bf16* __restrict__ wgt,
                                                 const bf16* __restrict__ bia,
                                                 bf16* __restrict__ out) {
  int r = blockIdx.x;
  const float* xr = x + (size_t)r * EE;
  int tid = threadIdx.x;
  float v0 = xr[tid], v1 = xr[tid + 256], v2 = xr[tid + 512];
  float s = v0 + v1 + v2;
  for (int o = 1; o < 64; o <<= 1) s += __shfl_xor(s, o, 64);
  __shared__ float red[4];
  int wv = tid >> 6;
  if ((tid & 63) == 0) red[wv] = s;
  __syncthreads();
  float mu = (red[0] + red[1] + red[2] + red[3]) * (1.f / 768.f);
  __syncthreads();
  float d0 = v0 - mu, d1 = v1 - mu, d2 = v2 - mu;
  float q = d0 * d0 + d1 * d1 + d2 * d2;
  for (int o = 1; o < 64; o <<= 1) q += __shfl_xor(q, o, 64);
  if ((tid & 63) == 0) red[wv] = q;
  __syncthreads();
  float var = (red[0] + red[1] + red[2] + red[3]) * (1.f / 768.f);
  float rs = rsqrtf(var + 1e-5f);
  bf16* orow = out + (size_t)r * EE;
  orow[tid]       = f2bf(d0 * rs * bf2f(wgt[tid])       + bf2f(bia[tid]));
  orow[tid + 256] = f2bf(d1 * rs * bf2f(wgt[tid + 256]) + bf2f(bia[tid + 256]));
  orow[tid + 512] = f2bf(d2 * rs * bf2f(wgt[tid + 512]) + bf2f(bia[tid + 512]));
}

// qkv (BT,3E) -> Q (B,H,T,HD), K (B,H,T,HD), Vt (B,H,HD,T)
__global__ __launch_bounds__(256) void split_qkv_kernel(const bf16* __restrict__ qkv,
                                                        bf16* __restrict__ Q,
                                                        bf16* __restrict__ Km,
                                                        bf16* __restrict__ Vt) {
  int idx = blockIdx.x * 256 + threadIdx.x;
  int r = idx / E3, c = idx % E3;
  int sec = c / EE, e = c % EE;
  int h = e >> 6, d = e & 63;
  int b = r >> 10, t = r & 1023;
  int bh = b * HH + h;
  bf16 v = qkv[(size_t)idx];
  if (sec == 0)      Q[((size_t)bh * TT + t) * HDIM + d] = v;
  else if (sec == 1) Km[((size_t)bh * TT + t) * HDIM + d] = v;
  else               Vt[((size_t)bh * HDIM + d) * TT + t] = v;
}

// ---------------- GEMM: C = A (MxK) @ Bt^T (Bt is NxK) ----------------
// LOGITS variant additionally computes per-block row (max, sumexp) partials
// and gathers the target logit, so the loss never re-reads logits from HBM.

template<int BM, int BN, bool LOGITS>
__global__ __launch_bounds__(256) void gemm_bt(const bf16* __restrict__ A,
                                               const bf16* __restrict__ Bt,
                                               const bf16* __restrict__ bias,
                                               bf16* __restrict__ outb,
                                               float* __restrict__ outf,
                                               const float* __restrict__ resid,
                                               int M, int N, int K, int gelu,
                                               const int* __restrict__ oflag,
                                               const int* __restrict__ tgt,
                                               float2* __restrict__ part,
                                               float* __restrict__ tgtval) {
  constexpr int IT = BM / 32;
  constexpr int JT = BN / 32;
  constexpr int ACH = BM / 64;
  constexpr int BCH = BN / 64;
  __shared__ __attribute__((aligned(16))) bf16 As[BM * 32];
  __shared__ __attribute__((aligned(16))) bf16 Bs[BN * 32];
  int f32o = (oflag != nullptr) && (*oflag != 0);
  int tid = threadIdx.x;
  int wave = tid >> 6, lane = tid & 63, low = lane & 15, quad = lane >> 4;

  // block -> tile mapping; supergroup swizzle for the logits GEMM (wte L2 reuse)
  int bxn, bym;
  if (LOGITS) {
    int nbx = gridDim.x, nby = gridDim.y;
    int id = blockIdx.y * nbx + blockIdx.x;
    const int GW = 16;
    int per = GW * nby;
    int chunk = id / per;
    int rem = id - chunk * per;
    int base = chunk * GW;
    int w = min(GW, nbx - base);
    bxn = base + rem % w;
    bym = rem / w;
  } else {
    bxn = blockIdx.x; bym = blockIdx.y;
  }
  int m0 = bym * BM, n0 = bxn * BN;

  int wm = (wave >> 1) * (BM / 2), wn = (wave & 1) * (BN / 2);
  f32x4 acc[IT][JT];
  f32x4 zero = {0.f, 0.f, 0.f, 0.f};
#pragma unroll
  for (int i = 0; i < IT; ++i)
#pragma unroll
    for (int j = 0; j < JT; ++j) acc[i][j] = zero;

  for (int kb = 0; kb < K; kb += 32) {
    __syncthreads();  // previous iteration's LDS readers done
#pragma unroll
    for (int c = 0; c < ACH; ++c) {
      int g = c * 256 + tid;
      async_load16(A + (size_t)(m0 + (g >> 2)) * K + kb + (g & 3) * 8, (char*)As + g * 16);
    }
#pragma unroll
    for (int c = 0; c < BCH; ++c) {
      int g = c * 256 + tid;
      async_load16(Bt + (size_t)(n0 + (g >> 2)) * K + kb + (g & 3) * 8, (char*)Bs + g * 16);
    }
    __syncthreads();  // barrier drains vmcnt -> LDS valid
    bf16x8 af[IT], bfr[JT];
#pragma unroll
    for (int i = 0; i < IT; ++i)
      af[i] = *(const bf16x8*)(As + (wm + i * 16 + low) * 32 + quad * 8);
#pragma unroll
    for (int j = 0; j < JT; ++j)
      bfr[j] = *(const bf16x8*)(Bs + (wn + j * 16 + low) * 32 + quad * 8);
#pragma unroll
    for (int i = 0; i < IT; ++i)
#pragma unroll
      for (int j = 0; j < JT; ++j)
        acc[i][j] = __builtin_amdgcn_mfma_f32_16x16x32_bf16(af[i], bfr[j], acc[i][j], 0, 0, 0);
  }

  // C/D layout: col=lane&15, row=quad*4+reg (m89/m91-verified)
  if (outb || outf || bias || resid) {
#pragma unroll
    for (int i = 0; i < IT; ++i)
#pragma unroll
      for (int j = 0; j < JT; ++j)
#pragma unroll
        for (int r = 0; r < 4; ++r) {
          int m = m0 + wm + i * 16 + quad * 4 + r;
          int n = n0 + wn + j * 16 + low;
          float v = acc[i][j][r];
          if (bias) v += bf2f(bias[n]);
          if (gelu) v = gelu_tanh(v);
          size_t idx = (size_t)m * N + n;
          if (resid) v += resid[idx];
          if (outf) outf[idx] = v;
          if (outb) {
            if (f32o) ((float*)outb)[idx] = v;
            else      outb[idx] = f2bf(v);
          }
        }
  }

  if constexpr (LOGITS) {
    // --- fused partial logsumexp over this block's BN columns + target gather ---
    __shared__ float2 prt[4][BM / 2];
#pragma unroll
    for (int i = 0; i < IT; ++i) {
#pragma unroll
      for (int r = 0; r < 4; ++r) {
        int mg = m0 + wm + i * 16 + quad * 4 + r;
        int tr = tgt[mg];
        float vmax = -1e30f;
#pragma unroll
        for (int j = 0; j < JT; ++j) {
          float v = acc[i][j][r];
          vmax = fmaxf(vmax, v);
          int n = n0 + wn + j * 16 + low;
          if (n == tr) tgtval[mg] = v;   // exactly one lane grid-wide matches
        }
        for (int oo = 1; oo < 16; oo <<= 1) vmax = fmaxf(vmax, __shfl_xor(vmax, oo, 64));
        float se = 0.f;
#pragma unroll
        for (int j = 0; j < JT; ++j) se += __expf(acc[i][j][r] - vmax);
        for (int oo = 1; oo < 16; oo <<= 1) se += __shfl_xor(se, oo, 64);
        if (low == 0) prt[wave][i * 16 + quad * 4 + r] = make_float2(vmax, se);
      }
    }
    __syncthreads();
    if (tid < BM) {
      // waves {0,1} cover rows [0,BM/2) (col halves), waves {2,3} rows [BM/2,BM)
      int half = tid >> 6, rowin = tid & 63;
      float2 a = prt[half * 2][rowin], b = prt[half * 2 + 1][rowin];
      float M2 = fmaxf(a.x, b.x);
      float S = a.y * __expf(a.x - M2) + b.y * __expf(b.x - M2);
      part[(size_t)(m0 + tid) * gridDim.x + bxn] = make_float2(M2, S);
    }
  }
}

// ---------------- flash attention (full, non-causal); ref scale = HD^0.5 = 8 ----------------

__global__ __launch_bounds__(64) void attn_kernel(const bf16* __restrict__ Q,
                                                  const bf16* __restrict__ Km,
                                                  const bf16* __restrict__ Vt,
                                                  bf16* __restrict__ y) {
  __shared__ __attribute__((aligned(16))) bf16 plds[16 * 32];
  int bh = blockIdx.x >> 6;            // T/16 = 64 q-tiles per (b,h)
  int q0 = (blockIdx.x & 63) << 4;
  int b = bh / HH, h = bh % HH;
  int lane = threadIdx.x, low = lane & 15, quad = lane >> 4;
  const bf16* Qb = Q + (size_t)bh * TT * HDIM;
  const bf16* Kb = Km + (size_t)bh * TT * HDIM;
  const bf16* Vb = Vt + (size_t)bh * HDIM * TT;

  bf16x8 aq0 = *(const bf16x8*)(Qb + (size_t)(q0 + low) * HDIM + quad * 8);
  bf16x8 aq1 = *(const bf16x8*)(Qb + (size_t)(q0 + low) * HDIM + 32 + quad * 8);

  f32x4 o[4];
  f32x4 zero = {0.f, 0.f, 0.f, 0.f};
  float mr[4], lr[4];
#pragma unroll
  for (int r = 0; r < 4; ++r) { o[r] = zero; mr[r] = -1e30f; lr[r] = 0.f; }

  for (int kt = 0; kt < TT; kt += 32) {
    bf16x8 bk00 = *(const bf16x8*)(Kb + (size_t)(kt + low) * HDIM + quad * 8);
    bf16x8 bk01 = *(const bf16x8*)(Kb + (size_t)(kt + low) * HDIM + 32 + quad * 8);
    bf16x8 bk10 = *(const bf16x8*)(Kb + (size_t)(kt + 16 + low) * HDIM + quad * 8);
    bf16x8 bk11 = *(const bf16x8*)(Kb + (size_t)(kt + 16 + low) * HDIM + 32 + quad * 8);
    f32x4 sa = zero, sb = zero;
    sa = __builtin_amdgcn_mfma_f32_16x16x32_bf16(aq0, bk00, sa, 0, 0, 0);
    sa = __builtin_amdgcn_mfma_f32_16x16x32_bf16(aq1, bk01, sa, 0, 0, 0);
    sb = __builtin_amdgcn_mfma_f32_16x16x32_bf16(aq0, bk10, sb, 0, 0, 0);
    sb = __builtin_amdgcn_mfma_f32_16x16x32_bf16(aq1, bk11, sb, 0, 0, 0);
#pragma unroll
    for (int r = 0; r < 4; ++r) {
      float s0 = sa[r] * 8.f, s1 = sb[r] * 8.f;   // reference multiplies by HD^0.5
      float tm = fmaxf(s0, s1);
      for (int oo = 1; oo < 16; oo <<= 1) tm = fmaxf(tm, __shfl_xor(tm, oo, 64));
      float mn = fmaxf(mr[r], tm);
      float alpha = __expf(mr[r] - mn);
      float p0 = __expf(s0 - mn), p1 = __expf(s1 - mn);
      float rs = p0 + p1;
      for (int oo = 1; oo < 16; oo <<= 1) rs += __shfl_xor(rs, oo, 64);
      lr[r] = lr[r] * alpha + rs;
      mr[r] = mn;
      o[0][r] *= alpha; o[1][r] *= alpha; o[2][r] *= alpha; o[3][r] *= alpha;
      plds[(quad * 4 + r) * 32 + low] = f2bf(p0);
      plds[(quad * 4 + r) * 32 + 16 + low] = f2bf(p1);
    }
    __syncthreads();  // C-layout -> A-layout via LDS
    bf16x8 pa = *(const bf16x8*)(plds + low * 32 + quad * 8);
#pragma unroll
    for (int fb = 0; fb < 4; ++fb) {
      bf16x8 bv = *(const bf16x8*)(Vb + (size_t)(fb * 16 + low) * TT + kt + quad * 8);
      o[fb] = __builtin_amdgcn_mfma_f32_16x16x32_bf16(pa, bv, o[fb], 0, 0, 0);
    }
    __syncthreads();
  }
#pragma unroll
  for (int fb = 0; fb < 4; ++fb)
#pragma unroll
    for (int r = 0; r < 4; ++r) {
      float val = o[fb][r] / lr[r];
      y[(size_t)(b * TT + q0 + quad * 4 + r) * EE + h * HDIM + fb * 16 + low] = f2bf(val);
    }
}

// ---------------- loss: fold per-block (max,sumexp) partials -> LSE -> mean ----------------

__global__ __launch_bounds__(256) void lse_reduce_kernel(const float2* __restrict__ part,
                                                         const float* __restrict__ tgtval,
                                                         float* __restrict__ acc, int NB) {
  int r = blockIdx.x;
  const float2* p = part + (size_t)r * NB;
  float m = -1e30f, s = 0.f;
  for (int j = threadIdx.x; j < NB; j += 256) {
    float2 v = p[j];
    float M = fmaxf(m, v.x);
    s = s * __expf(m - M) + v.y * __expf(v.x - M);
    m = M;
  }
  for (int o = 1; o < 64; o <<= 1) {
    float m2 = __shfl_xor(m, o, 64), s2 = __shfl_xor(s, o, 64);
    float M = fmaxf(m, m2);
    s = s * __expf(m - M) + s2 * __expf(m2 - M);
    m = M;
  }
  __shared__ float sm[4], ss[4];
  int wv = threadIdx.x >> 6;
  if ((threadIdx.x & 63) == 0) { sm[wv] = m; ss[wv] = s; }
  __syncthreads();
  if (threadIdx.x == 0) {
    float M = sm[0], S = ss[0];
    for (int i = 1; i < 4; ++i) {
      float M2 = fmaxf(M, sm[i]);
      S = S * __expf(M - M2) + ss[i] * __expf(sm[i] - M2);
      M = M2;
    }
    float lse = M + logf(S);
    atomicAdd(acc, (lse - tgtval[r]) * (1.f / (float)BT));
  }
}

// ---------------- host ----------------

extern "C" void kernel_launch(void* const* d_in, const int* in_sizes, int n_in,
                              void* d_out, int out_size, void* d_ws, size_t ws_size,
                              hipStream_t stream) {
  const int* t[5];
  for (int i = 0; i < 5; ++i) t[i] = (const int*)d_in[i];
  const void* wte_r   = d_in[5];
  const void* wpe_r   = d_in[6];
  const void* ln1w_r  = d_in[7];
  const void* ln1b_r  = d_in[8];
  const void* ln2w_r  = d_in[9];
  const void* ln2b_r  = d_in[10];
  const void* attnw_r = d_in[11];
  const void* attnb_r = d_in[12];
  const void* projw_r = d_in[13];
  const void* projb_r = d_in[14];
  const void* fc1w_r  = d_in[15];
  const void* fc1b_r  = d_in[16];
  const void* fc2w_r  = d_in[17];
  const void* fc2b_r  = d_in[18];

  char* w = (char*)d_ws;
  int* flag    = (int*)w;
  float* loss  = (float*)(w + 64); w += 256;
  float* x     = (float*)w; w += (size_t)BT * EE * 4;
  bf16* h      = (bf16*)w;  w += (size_t)BT * EE * 2;
  bf16* qkv    = (bf16*)w;  w += (size_t)BT * E3 * 2;
  bf16* g      = (bf16*)w;  w += (size_t)BT * E3 * 2;
  bf16* Q      = (bf16*)w;  w += (size_t)BT * EE * 2;
  bf16* Km     = (bf16*)w;  w += (size_t)BT * EE * 2;
  bf16* Vt     = (bf16*)w;  w += (size_t)BT * EE * 2;
  bf16* y      = (bf16*)w;  w += (size_t)BT * EE * 2;
  bf16* xb     = (bf16*)w;  w += (size_t)BT * EE * 2;
  bf16* aT     = (bf16*)w;  w += (size_t)E3 * EE * 2;   // per-layer transposed weights
  bf16* pT     = (bf16*)w;  w += (size_t)EE * EE * 2;
  bf16* f1T    = (bf16*)w;  w += (size_t)E3 * EE * 2;
  bf16* f2T    = (bf16*)w;  w += (size_t)EE * E3 * 2;
  bf16* wpeB   = (bf16*)w;  w += (size_t)TT * EE * 2;
  bf16* ln1wB  = (bf16*)w;  w += (size_t)LL * EE * 2;
  bf16* ln1bB  = (bf16*)w;  w += (size_t)LL * EE * 2;
  bf16* ln2wB  = (bf16*)w;  w += (size_t)LL * EE * 2;
  bf16* ln2bB  = (bf16*)w;  w += (size_t)LL * EE * 2;
  bf16* attnbB = (bf16*)w;  w += (size_t)LL * E3 * 2;
  bf16* projbB = (bf16*)w;  w += (size_t)LL * EE * 2;
  bf16* fc1bB  = (bf16*)w;  w += (size_t)LL * E3 * 2;
  bf16* fc2bB  = (bf16*)w;  w += (size_t)LL * EE * 2;
  float2* part = (float2*)w; w += (size_t)BT * NBLOG * sizeof(float2);  // 4.1 MB LSE partials
  float* tgtv  = (float*)w;  w += (size_t)BT * 4;
  bf16* wteB   = (bf16*)w;  w += (size_t)VV * EE * 2;   // last: only used in mode A
  size_t need_a = (size_t)(w - (char*)d_ws);
  int modeA = ws_size >= need_a;

  bf16* out = (bf16*)d_out;
  const bf16* wte_use = modeA ? wteB : (const bf16*)wte_r;

  detect_kernel<<<1, 1, 0, stream>>>((const unsigned*)ln1w_r, flag, modeA ? 0 : 1);
  zero_loss_kernel<<<1, 1, 0, stream>>>(loss);

  // param conversions (copies when already bf16)
  if (modeA)
    convert_kernel<<<((size_t)VV * EE + 255) / 256, 256, 0, stream>>>(wte_r, wteB, (long)VV * EE, flag);
  convert_kernel<<<((size_t)TT * EE + 255) / 256, 256, 0, stream>>>(wpe_r, wpeB, (long)TT * EE, flag);
  convert_kernel<<<(LL * EE + 255) / 256, 256, 0, stream>>>(ln1w_r, ln1wB, LL * EE, flag);
  convert_kernel<<<(LL * EE + 255) / 256, 256, 0, stream>>>(ln1b_r, ln1bB, LL * EE, flag);
  convert_kernel<<<(LL * EE + 255) / 256, 256, 0, stream>>>(ln2w_r, ln2wB, LL * EE, flag);
  convert_kernel<<<(LL * EE + 255) / 256, 256, 0, stream>>>(ln2b_r, ln2bB, LL * EE, flag);
  convert_kernel<<<(LL * E3 + 255) / 256, 256, 0, stream>>>(attnb_r, attnbB, LL * E3, flag);
  convert_kernel<<<(LL * EE + 255) / 256, 256, 0, stream>>>(projb_r, projbB, LL * EE, flag);
  convert_kernel<<<(LL * E3 + 255) / 256, 256, 0, stream>>>(fc1b_r, fc1bB, LL * E3, flag);
  convert_kernel<<<(LL * EE + 255) / 256, 256, 0, stream>>>(fc2b_r, fc2bB, LL * EE, flag);

  const bf16* wpe_use = modeA ? wpeB : (const bf16*)wpe_r;

  for (int i = 0; i < LL; ++i) {
    // per-layer weight transposes (K x N -> N x K, bf16)
    transpose_kernel<<<dim3(E3/32, EE/32), dim3(32, 8), 0, stream>>>(attnw_r, aT, EE, E3, i, flag);
    transpose_kernel<<<dim3(EE/32, EE/32), dim3(32, 8), 0, stream>>>(projw_r, pT, EE, EE, i, flag);
    transpose_kernel<<<dim3(E3/32, EE/32), dim3(32, 8), 0, stream>>>(fc1w_r, f1T, EE, E3, i, flag);
    transpose_kernel<<<dim3(EE/32, E3/32), dim3(32, 8), 0, stream>>>(fc2w_r, f2T, E3, EE, i, flag);

    embed_kernel<<<BT, 256, 0, stream>>>(t[i], wte_use, wpe_use, x);
    ln_kernel<<<BT, 256, 0, stream>>>(x, ln1wB + i * EE, ln1bB + i * EE, h);
    gemm_bt<128, 128, false><<<dim3(E3/128, BT/128), 256, 0, stream>>>(
        h, aT, attnbB + i * E3, qkv, nullptr, nullptr, BT, E3, EE, 0, nullptr,
        nullptr, nullptr, nullptr);
    split_qkv_kernel<<<(BT * E3) / 256, 256, 0, stream>>>(qkv, Q, Km, Vt);
    attn_kernel<<<BB * HH * (TT / 16), 64, 0, stream>>>(Q, Km, Vt, y);
    gemm_bt<64, 64, false><<<dim3(EE/64, BT/64), 256, 0, stream>>>(
        y, pT, projbB + i * EE, nullptr, x, x, BT, EE, EE, 0, nullptr,
        nullptr, nullptr, nullptr);
    ln_kernel<<<BT, 256, 0, stream>>>(x, ln2wB + i * EE, ln2bB + i * EE, h);
    gemm_bt<128, 128, false><<<dim3(E3/128, BT/128), 256, 0, stream>>>(
        h, f1T, fc1bB + i * E3, g, nullptr, nullptr, BT, E3, EE, 1, nullptr,
        nullptr, nullptr, nullptr);
    gemm_bt<64, 64, false><<<dim3(EE/64, BT/64), 256, 0, stream>>>(
        g, f2T, fc2bB + i * EE, xb, x, x, BT, EE, E3, 0, nullptr,
        nullptr, nullptr, nullptr);
    // logits GEMM: fused partial-LSE; only the final layer stores logits to out
    gemm_bt<128, 128, true><<<dim3(NBLOG, BT/128), 256, 0, stream>>>(
        xb, wte_use, nullptr, (i == LL - 1) ? out : nullptr, nullptr, nullptr,
        BT, VV, EE, 0, flag, t[i + 1], part, tgtv);
    lse_reduce_kernel<<<BT, 256, 0, stream>>>(part, tgtv, loss, NBLOG);
  }
  write_loss_kernel<<<1, 1, 0, stream>>>(loss, (void*)d_out, flag);
}

// Round 2
// 2065.326 us; speedup vs baseline: 1.2117x; 1.0645x over previous
//
#include <hip/hip_runtime.h>
#include <hip/hip_bf16.h>
#include <math.h>

#define BB 2
#define TT 1024
#define VV 32000
#define EE 768
#define HH 12
#define LL 4
#define HDIM 64
#define BT (BB*TT)   // 2048
#define E3 (3*EE)    // 2304
#define NBX 125      // 32000/256 n-blocks in 256-tile logits GEMM

typedef __hip_bfloat16 bf16;
typedef __attribute__((ext_vector_type(8))) short bf16x8;
typedef __attribute__((ext_vector_type(4))) float f32x4;

__device__ __forceinline__ float bf2f(bf16 v) { return __bfloat162float(v); }
__device__ __forceinline__ bf16 f2bf(float v) { return __float2bfloat16(v); }

__device__ __forceinline__ void async_load16(const void* g, void* l) {
  __builtin_amdgcn_global_load_lds((const __attribute__((address_space(1))) void*)g,
                                   (__attribute__((address_space(3))) void*)l, 16, 0, 0);
}

__device__ __forceinline__ float gelu_tanh(float x) {
  float u = 0.7978845608028654f * (x + 0.044715f * x * x * x);
  return 0.5f * x * (1.0f + tanhf(u));
}

// ---------------- dtype detect + conversion ----------------

__global__ void detect_kernel(const unsigned* __restrict__ raw, int* flag, int force_bf16) {
  if (force_bf16) { *flag = 0; return; }
  *flag = (raw[0] == 0x3F800000u && raw[1] == 0x3F800000u) ? 1 : 0;
}

__global__ __launch_bounds__(256) void convert_kernel(const void* __restrict__ in,
                                                      bf16* __restrict__ out, long n,
                                                      const int* __restrict__ flag) {
  long i = (long)blockIdx.x * 256 + threadIdx.x;
  if (i >= n) return;
  int f = *flag;
  out[i] = f ? f2bf(((const float*)in)[i]) : ((const bf16*)in)[i];
}

__global__ void zero_loss_kernel(float* p) { *p = 0.f; }

__global__ void write_loss_kernel(const float* p, void* out, const int* flag) {
  if (*flag) ((float*)out)[(size_t)BT * VV] = *p;
  else       ((bf16*)out)[(size_t)BT * VV] = f2bf(*p);
}

// one layer of a (L,R,C) tensor -> (C,R) bf16
__global__ __launch_bounds__(256) void transpose_kernel(const void* __restrict__ in,
                                                        bf16* __restrict__ out,
                                                        int R, int C, int layer,
                                                        const int* __restrict__ flag) {
  __shared__ bf16 tile[32][33];
  int f = *flag;
  const float* inf = (const float*)in + (size_t)layer * R * C;
  const bf16* inb  = (const bf16*)in  + (size_t)layer * R * C;
  int r0 = blockIdx.y * 32, c0 = blockIdx.x * 32;
#pragma unroll
  for (int i = 0; i < 4; ++i) {
    size_t idx = (size_t)(r0 + threadIdx.y + i * 8) * C + c0 + threadIdx.x;
    tile[threadIdx.y + i * 8][threadIdx.x] = f ? f2bf(inf[idx]) : inb[idx];
  }
  __syncthreads();
#pragma unroll
  for (int i = 0; i < 4; ++i) {
    int c = c0 + threadIdx.y + i * 8;
    out[(size_t)c * R + r0 + threadIdx.x] = tile[threadIdx.x][threadIdx.y + i * 8];
  }
}

// ---------------- model kernels (all consume bf16 copies) ----------------

__global__ __launch_bounds__(256) void embed_kernel(const int* __restrict__ tok,
                                                    const bf16* __restrict__ wte,
                                                    const bf16* __restrict__ wpe,
                                                    float* __restrict__ x) {
  int r = blockIdx.x;
  int tk = tok[r];
  int t = r & (TT - 1);
#pragma unroll
  for (int i = 0; i < 3; ++i) {
    int e = threadIdx.x + i * 256;
    x[(size_t)r * EE + e] = bf2f(wte[(size_t)tk * EE + e]) + bf2f(wpe[(size_t)t * EE + e]);
  }
}

__global__ __launch_bounds__(256) void ln_kernel(const float* __restrict__ x,
                                                 const bf16* __restrict__ wgt,
                                                 const bf16* __restrict__ bia,
                                                 bf16* __restrict__ out) {
  int r = blockIdx.x;
  const float* xr = x + (size_t)r * EE;
  int tid = threadIdx.x;
  float v0 = xr[tid], v1 = xr[tid + 256], v2 = xr[tid + 512];
  float s = v0 + v1 + v2;
  for (int o = 1; o < 64; o <<= 1) s += __shfl_xor(s, o, 64);
  __shared__ float red[4];
  int wv = tid >> 6;
  if ((tid & 63) == 0) red[wv] = s;
  __syncthreads();
  float mu = (red[0] + red[1] + red[2] + red[3]) * (1.f / 768.f);
  __syncthreads();
  float d0 = v0 - mu, d1 = v1 - mu, d2 = v2 - mu;
  float q = d0 * d0 + d1 * d1 + d2 * d2;
  for (int o = 1; o < 64; o <<= 1) q += __shfl_xor(q, o, 64);
  if ((tid & 63) == 0) red[wv] = q;
  __syncthreads();
  float var = (red[0] + red[1] + red[2] + red[3]) * (1.f / 768.f);
  float rs = rsqrtf(var + 1e-5f);
  bf16* orow = out + (size_t)r * EE;
  orow[tid]       = f2bf(d0 * rs * bf2f(wgt[tid])       + bf2f(bia[tid]));
  orow[tid + 256] = f2bf(d1 * rs * bf2f(wgt[tid + 256]) + bf2f(bia[tid + 256]));
  orow[tid + 512] = f2bf(d2 * rs * bf2f(wgt[tid + 512]) + bf2f(bia[tid + 512]));
}

// qkv (BT,3E) -> Q (B,H,T,HD), K (B,H,T,HD), Vt (B,H,HD,T)
__global__ __launch_bounds__(256) void split_qkv_kernel(const bf16* __restrict__ qkv,
                                                        bf16* __restrict__ Q,
                                                        bf16* __restrict__ Km,
                                                        bf16* __restrict__ Vt) {
  int idx = blockIdx.x * 256 + threadIdx.x;
  int r = idx / E3, c = idx % E3;
  int sec = c / EE, e = c % EE;
  int h = e >> 6, d = e & 63;
  int b = r >> 10, t = r & 1023;
  int bh = b * HH + h;
  bf16 v = qkv[(size_t)idx];
  if (sec == 0)      Q[((size_t)bh * TT + t) * HDIM + d] = v;
  else if (sec == 1) Km[((size_t)bh * TT + t) * HDIM + d] = v;
  else               Vt[((size_t)bh * HDIM + d) * TT + t] = v;
}

// ---------------- GEMM: C = A (MxK) @ Bt^T (Bt is NxK) — 128/64 tile, 2-barrier loop ----------------

template<int BM, int BN>
__global__ __launch_bounds__(256) void gemm_bt(const bf16* __restrict__ A,
                                               const bf16* __restrict__ Bt,
                                               const bf16* __restrict__ bias,
                                               bf16* __restrict__ outb,
                                               float* __restrict__ outf,
                                               const float* __restrict__ resid,
                                               int M, int N, int K, int gelu) {
  constexpr int IT = BM / 32;
  constexpr int JT = BN / 32;
  constexpr int ACH = BM / 64;
  constexpr int BCH = BN / 64;
  __shared__ __attribute__((aligned(16))) bf16 As[BM * 32];
  __shared__ __attribute__((aligned(16))) bf16 Bs[BN * 32];
  int tid = threadIdx.x;
  int wave = tid >> 6, lane = tid & 63, low = lane & 15, quad = lane >> 4;
  int m0 = blockIdx.y * BM, n0 = blockIdx.x * BN;
  int wm = (wave >> 1) * (BM / 2), wn = (wave & 1) * (BN / 2);
  f32x4 acc[IT][JT];
  f32x4 zero = {0.f, 0.f, 0.f, 0.f};
#pragma unroll
  for (int i = 0; i < IT; ++i)
#pragma unroll
    for (int j = 0; j < JT; ++j) acc[i][j] = zero;

  for (int kb = 0; kb < K; kb += 32) {
    __syncthreads();  // previous iteration's LDS readers done
#pragma unroll
    for (int c = 0; c < ACH; ++c) {
      int g = c * 256 + tid;
      async_load16(A + (size_t)(m0 + (g >> 2)) * K + kb + (g & 3) * 8, (char*)As + g * 16);
    }
#pragma unroll
    for (int c = 0; c < BCH; ++c) {
      int g = c * 256 + tid;
      async_load16(Bt + (size_t)(n0 + (g >> 2)) * K + kb + (g & 3) * 8, (char*)Bs + g * 16);
    }
    __syncthreads();  // barrier drains vmcnt -> LDS valid
    bf16x8 af[IT], bfr[JT];
#pragma unroll
    for (int i = 0; i < IT; ++i)
      af[i] = *(const bf16x8*)(As + (wm + i * 16 + low) * 32 + quad * 8);
#pragma unroll
    for (int j = 0; j < JT; ++j)
      bfr[j] = *(const bf16x8*)(Bs + (wn + j * 16 + low) * 32 + quad * 8);
#pragma unroll
    for (int i = 0; i < IT; ++i)
#pragma unroll
      for (int j = 0; j < JT; ++j)
        acc[i][j] = __builtin_amdgcn_mfma_f32_16x16x32_bf16(af[i], bfr[j], acc[i][j], 0, 0, 0);
  }

  // C/D layout: col=lane&15, row=quad*4+reg (m89/m91-verified)
#pragma unroll
  for (int i = 0; i < IT; ++i)
#pragma unroll
    for (int j = 0; j < JT; ++j)
#pragma unroll
      for (int r = 0; r < 4; ++r) {
        int m = m0 + wm + i * 16 + quad * 4 + r;
        int n = n0 + wn + j * 16 + low;
        float v = acc[i][j][r];
        if (bias) v += bf2f(bias[n]);
        if (gelu) v = gelu_tanh(v);
        size_t idx = (size_t)m * N + n;
        if (resid) v += resid[idx];
        if (outf) outf[idx] = v;
        if (outb) outb[idx] = f2bf(v);
      }
}

// ---------------- logits GEMM: 256x256 tile, BK=64, 8 waves, pipelined + fused LSE ----------------
// LDS tile layout (per 256x64 operand tile, 32 KiB): 16x32-bf16 subtiles (1024 B each),
// [rowBlk(16)][colBlk(2)][r(16)][c(32)], with st_16x32 swizzle: byte ^= ((byte>>9)&1)<<5.
// global_load_lds writes LINEARLY (wave-uniform base + lane*16), so the global SOURCE is
// pre-swizzled (rule #21): chunk g fetches logical chunk ge = g ^ (((g>>5)&1)<<1).

__device__ __forceinline__ void stage_tile256(const bf16* __restrict__ Gp,
                                              int kb, char* ldsTile, int tid) {
#pragma unroll
  for (int i = 0; i < 4; ++i) {
    int g = i * 512 + tid;
    int ge = g ^ (((g >> 5) & 1) << 1);
    int row = ((ge >> 7) << 4) | ((ge >> 2) & 15);
    int col = (((ge >> 6) & 1) << 5) | ((ge & 3) << 3);
    async_load16(Gp + (size_t)row * EE + kb + col, ldsTile + g * 16);
  }
}

__global__ __launch_bounds__(512, 2) void gemm256_logits(
    const bf16* __restrict__ A,      // (2048, 768)
    const bf16* __restrict__ Bt,     // (32000, 768) = wte
    void* __restrict__ outp,         // final layer: logits out (f32 when *oflag) or nullptr
    const int* __restrict__ oflag,
    const int* __restrict__ tgt,
    float2* __restrict__ part,       // (2048, 125) per-block LSE partials
    float* __restrict__ tgtval) {
  __shared__ __attribute__((aligned(16))) char ldsRaw[2][2][32768];  // [dbuf][A/B] 128 KiB
  constexpr int NT = EE / 64;  // 12 K-tiles
  int tid = threadIdx.x;
  int wid = tid >> 6, lane = tid & 63, low = lane & 15, quad = lane >> 4;
  int wr = wid >> 2, wc = wid & 3;             // 2M x 4N waves; wave tile 128x64

  // XCD-aware mapping: each XCD owns one 256-row A panel, sweeps all 125 n-blocks
  int l = blockIdx.y * NBX + blockIdx.x;       // 0..999 (1000 % 8 == 0 -> bijective)
  int l2 = (l & 7) * NBX + (l >> 3);
  int bym = l2 / NBX, bxn = l2 - bym * NBX;
  int m0 = bym * 256, n0 = bxn * 256;

  const bf16* Ab = A + (size_t)m0 * EE;
  const bf16* Bb = Bt + (size_t)n0 * EE;

  f32x4 acc[8][4];
  f32x4 zero = {0.f, 0.f, 0.f, 0.f};
#pragma unroll
  for (int mi = 0; mi < 8; ++mi)
#pragma unroll
    for (int nj = 0; nj < 4; ++nj) acc[mi][nj] = zero;

  // prologue: stage tile 0 -> buf 0
  stage_tile256(Ab, 0, ldsRaw[0][0], tid);
  stage_tile256(Bb, 0, ldsRaw[0][1], tid);

  for (int t = 0; t < NT; ++t) {
    int cur = t & 1;
    if (t + 1 < NT) {
      // stage tile t+1 into the buffer last read in iteration t-1 (reads completed
      // before the trailing barrier of iter t-1, which precedes this in program order)
      stage_tile256(Ab, (t + 1) * 64, ldsRaw[cur ^ 1][0], tid);
      stage_tile256(Bb, (t + 1) * 64, ldsRaw[cur ^ 1][1], tid);
      asm volatile("s_waitcnt vmcnt(8)" ::: "memory");   // tile t landed; t+1 in flight
    } else {
      asm volatile("s_waitcnt vmcnt(0)" ::: "memory");
    }
    asm volatile("s_barrier" ::: "memory");              // all waves' tile-t loads landed
    const char* At = ldsRaw[cur][0];
    const char* Bs = ldsRaw[cur][1];
#pragma unroll
    for (int ks = 0; ks < 2; ++ks) {
      bf16x8 af[8], bfr[4];
#pragma unroll
      for (int mi = 0; mi < 8; ++mi) {
        int s = ((wr * 8 + mi) << 11) | (ks << 10) | (low << 6) | (quad << 4);
        s ^= (low >> 3) << 5;
        af[mi] = *(const bf16x8*)(At + s);
      }
#pragma unroll
      for (int nj = 0; nj < 4; ++nj) {
        int s = ((wc * 4 + nj) << 11) | (ks << 10) | (low << 6) | (quad << 4);
        s ^= (low >> 3) << 5;
        bfr[nj] = *(const bf16x8*)(Bs + s);
      }
      asm volatile("s_barrier" ::: "memory");            // align wave phases
      asm volatile("s_waitcnt lgkmcnt(0)" ::: "memory");
      __builtin_amdgcn_sched_barrier(0);
      __builtin_amdgcn_s_setprio(1);
#pragma unroll
      for (int mi = 0; mi < 8; ++mi)
#pragma unroll
        for (int nj = 0; nj < 4; ++nj)
          acc[mi][nj] = __builtin_amdgcn_mfma_f32_16x16x32_bf16(af[mi], bfr[nj], acc[mi][nj], 0, 0, 0);
      __builtin_amdgcn_s_setprio(0);
      asm volatile("s_barrier" ::: "memory");            // readers of buf[cur] done (phase)
    }
  }

  // ---- epilogue ----
  // C/D layout: col=lane&15, row=quad*4+reg
  if (outp) {
    int f32o = (oflag != nullptr) && (*oflag != 0);
    if (f32o) {
      float* of = (float*)outp;
#pragma unroll
      for (int mi = 0; mi < 8; ++mi)
#pragma unroll
        for (int nj = 0; nj < 4; ++nj)
#pragma unroll
          for (int r = 0; r < 4; ++r) {
            int m = m0 + wr * 128 + mi * 16 + quad * 4 + r;
            int n = n0 + wc * 64 + nj * 16 + low;
            of[(size_t)m * VV + n] = acc[mi][nj][r];
          }
    } else {
      bf16* ob = (bf16*)outp;
#pragma unroll
      for (int mi = 0; mi < 8; ++mi)
#pragma unroll
        for (int nj = 0; nj < 4; ++nj)
#pragma unroll
          for (int r = 0; r < 4; ++r) {
            int m = m0 + wr * 128 + mi * 16 + quad * 4 + r;
            int n = n0 + wc * 64 + nj * 16 + low;
            ob[(size_t)m * VV + n] = f2bf(acc[mi][nj][r]);
          }
    }
  }

  // per-row (max, sumexp) over this block's 256 columns + target-logit gather
  float2* cmb = (float2*)ldsRaw;   // [wc strip 0..3][row 0..255], 8 KiB (K-loop LDS done)
#pragma unroll
  for (int mi = 0; mi < 8; ++mi) {
#pragma unroll
    for (int r = 0; r < 4; ++r) {
      int rowl = wr * 128 + mi * 16 + quad * 4 + r;
      int rowg = m0 + rowl;
      int trg = tgt[rowg];
      float vmax = fmaxf(fmaxf(acc[mi][0][r], acc[mi][1][r]),
                         fmaxf(acc[mi][2][r], acc[mi][3][r]));
#pragma unroll
      for (int nj = 0; nj < 4; ++nj) {
        int n = n0 + wc * 64 + nj * 16 + low;
        if (n == trg) tgtval[rowg] = acc[mi][nj][r];   // exactly one lane grid-wide
      }
      for (int o = 1; o < 16; o <<= 1) vmax = fmaxf(vmax, __shfl_xor(vmax, o, 64));
      float se = 0.f;
#pragma unroll
      for (int nj = 0; nj < 4; ++nj) se += __expf(acc[mi][nj][r] - vmax);
      for (int o = 1; o < 16; o <<= 1) se += __shfl_xor(se, o, 64);
      if (low == 0) cmb[wc * 256 + rowl] = make_float2(vmax, se);
    }
  }
  __syncthreads();
  if (tid < 256) {
    float2 a = cmb[tid], b = cmb[256 + tid], c = cmb[512 + tid], d = cmb[768 + tid];
    float M = fmaxf(fmaxf(a.x, b.x), fmaxf(c.x, d.x));
    float S = a.y * __expf(a.x - M) + b.y * __expf(b.x - M) +
              c.y * __expf(c.x - M) + d.y * __expf(d.x - M);
    part[(size_t)(m0 + tid) * NBX + bxn] = make_float2(M, S);
  }
}

// ---------------- flash attention (full, non-causal); ref scale = HD^0.5 = 8 ----------------

__global__ __launch_bounds__(64) void attn_kernel(const bf16* __restrict__ Q,
                                                  const bf16* __restrict__ Km,
                                                  const bf16* __restrict__ Vt,
                                                  bf16* __restrict__ y) {
  __shared__ __attribute__((aligned(16))) bf16 plds[16 * 32];
  int bh = blockIdx.x >> 6;            // T/16 = 64 q-tiles per (b,h)
  int q0 = (blockIdx.x & 63) << 4;
  int b = bh / HH, h = bh % HH;
  int lane = threadIdx.x, low = lane & 15, quad = lane >> 4;
  const bf16* Qb = Q + (size_t)bh * TT * HDIM;
  const bf16* Kb = Km + (size_t)bh * TT * HDIM;
  const bf16* Vb = Vt + (size_t)bh * HDIM * TT;

  bf16x8 aq0 = *(const bf16x8*)(Qb + (size_t)(q0 + low) * HDIM + quad * 8);
  bf16x8 aq1 = *(const bf16x8*)(Qb + (size_t)(q0 + low) * HDIM + 32 + quad * 8);

  f32x4 o[4];
  f32x4 zero = {0.f, 0.f, 0.f, 0.f};
  float mr[4], lr[4];
#pragma unroll
  for (int r = 0; r < 4; ++r) { o[r] = zero; mr[r] = -1e30f; lr[r] = 0.f; }

  for (int kt = 0; kt < TT; kt += 32) {
    bf16x8 bk00 = *(const bf16x8*)(Kb + (size_t)(kt + low) * HDIM + quad * 8);
    bf16x8 bk01 = *(const bf16x8*)(Kb + (size_t)(kt + low) * HDIM + 32 + quad * 8);
    bf16x8 bk10 = *(const bf16x8*)(Kb + (size_t)(kt + 16 + low) * HDIM + quad * 8);
    bf16x8 bk11 = *(const bf16x8*)(Kb + (size_t)(kt + 16 + low) * HDIM + 32 + quad * 8);
    f32x4 sa = zero, sb = zero;
    sa = __builtin_amdgcn_mfma_f32_16x16x32_bf16(aq0, bk00, sa, 0, 0, 0);
    sa = __builtin_amdgcn_mfma_f32_16x16x32_bf16(aq1, bk01, sa, 0, 0, 0);
    sb = __builtin_amdgcn_mfma_f32_16x16x32_bf16(aq0, bk10, sb, 0, 0, 0);
    sb = __builtin_amdgcn_mfma_f32_16x16x32_bf16(aq1, bk11, sb, 0, 0, 0);
#pragma unroll
    for (int r = 0; r < 4; ++r) {
      float s0 = sa[r] * 8.f, s1 = sb[r] * 8.f;   // reference multiplies by HD^0.5
      float tm = fmaxf(s0, s1);
      for (int oo = 1; oo < 16; oo <<= 1) tm = fmaxf(tm, __shfl_xor(tm, oo, 64));
      float mn = fmaxf(mr[r], tm);
      float alpha = __expf(mr[r] - mn);
      float p0 = __expf(s0 - mn), p1 = __expf(s1 - mn);
      float rs = p0 + p1;
      for (int oo = 1; oo < 16; oo <<= 1) rs += __shfl_xor(rs, oo, 64);
      lr[r] = lr[r] * alpha + rs;
      mr[r] = mn;
      o[0][r] *= alpha; o[1][r] *= alpha; o[2][r] *= alpha; o[3][r] *= alpha;
      plds[(quad * 4 + r) * 32 + low] = f2bf(p0);
      plds[(quad * 4 + r) * 32 + 16 + low] = f2bf(p1);
    }
    __syncthreads();  // C-layout -> A-layout via LDS
    bf16x8 pa = *(const bf16x8*)(plds + low * 32 + quad * 8);
#pragma unroll
    for (int fb = 0; fb < 4; ++fb) {
      bf16x8 bv = *(const bf16x8*)(Vb + (size_t)(fb * 16 + low) * TT + kt + quad * 8);
      o[fb] = __builtin_amdgcn_mfma_f32_16x16x32_bf16(pa, bv, o[fb], 0, 0, 0);
    }
    __syncthreads();
  }
#pragma unroll
  for (int fb = 0; fb < 4; ++fb)
#pragma unroll
    for (int r = 0; r < 4; ++r) {
      float val = o[fb][r] / lr[r];
      y[(size_t)(b * TT + q0 + quad * 4 + r) * EE + h * HDIM + fb * 16 + low] = f2bf(val);
    }
}

// ---------------- loss: fold per-block (max,sumexp) partials -> LSE -> mean ----------------

__global__ __launch_bounds__(256) void lse_reduce_kernel(const float2* __restrict__ part,
                                                         const float* __restrict__ tgtval,
                                                         float* __restrict__ acc, int NB) {
  int r = blockIdx.x;
  const float2* p = part + (size_t)r * NB;
  float m = -1e30f, s = 0.f;
  for (int j = threadIdx.x; j < NB; j += 256) {
    float2 v = p[j];
    float M = fmaxf(m, v.x);
    s = s * __expf(m - M) + v.y * __expf(v.x - M);
    m = M;
  }
  for (int o = 1; o < 64; o <<= 1) {
    float m2 = __shfl_xor(m, o, 64), s2 = __shfl_xor(s, o, 64);
    float M = fmaxf(m, m2);
    s = s * __expf(m - M) + s2 * __expf(m2 - M);
    m = M;
  }
  __shared__ float sm[4], ss[4];
  int wv = threadIdx.x >> 6;
  if ((threadIdx.x & 63) == 0) { sm[wv] = m; ss[wv] = s; }
  __syncthreads();
  if (threadIdx.x == 0) {
    float M = sm[0], S = ss[0];
    for (int i = 1; i < 4; ++i) {
      float M2 = fmaxf(M, sm[i]);
      S = S * __expf(M - M2) + ss[i] * __expf(sm[i] - M2);
      M = M2;
    }
    float lse = M + logf(S);
    atomicAdd(acc, (lse - tgtval[r]) * (1.f / (float)BT));
  }
}

// ---------------- host ----------------

extern "C" void kernel_launch(void* const* d_in, const int* in_sizes, int n_in,
                              void* d_out, int out_size, void* d_ws, size_t ws_size,
                              hipStream_t stream) {
  const int* t[5];
  for (int i = 0; i < 5; ++i) t[i] = (const int*)d_in[i];
  const void* wte_r   = d_in[5];
  const void* wpe_r   = d_in[6];
  const void* ln1w_r  = d_in[7];
  const void* ln1b_r  = d_in[8];
  const void* ln2w_r  = d_in[9];
  const void* ln2b_r  = d_in[10];
  const void* attnw_r = d_in[11];
  const void* attnb_r = d_in[12];
  const void* projw_r = d_in[13];
  const void* projb_r = d_in[14];
  const void* fc1w_r  = d_in[15];
  const void* fc1b_r  = d_in[16];
  const void* fc2w_r  = d_in[17];
  const void* fc2b_r  = d_in[18];

  char* w = (char*)d_ws;
  int* flag    = (int*)w;
  float* loss  = (float*)(w + 64); w += 256;
  float* x     = (float*)w; w += (size_t)BT * EE * 4;
  bf16* h      = (bf16*)w;  w += (size_t)BT * EE * 2;
  bf16* qkv    = (bf16*)w;  w += (size_t)BT * E3 * 2;
  bf16* g      = (bf16*)w;  w += (size_t)BT * E3 * 2;
  bf16* Q      = (bf16*)w;  w += (size_t)BT * EE * 2;
  bf16* Km     = (bf16*)w;  w += (size_t)BT * EE * 2;
  bf16* Vt     = (bf16*)w;  w += (size_t)BT * EE * 2;
  bf16* y      = (bf16*)w;  w += (size_t)BT * EE * 2;
  bf16* xb     = (bf16*)w;  w += (size_t)BT * EE * 2;
  bf16* aT     = (bf16*)w;  w += (size_t)E3 * EE * 2;   // per-layer transposed weights
  bf16* pT     = (bf16*)w;  w += (size_t)EE * EE * 2;
  bf16* f1T    = (bf16*)w;  w += (size_t)E3 * EE * 2;
  bf16* f2T    = (bf16*)w;  w += (size_t)EE * E3 * 2;
  bf16* wpeB   = (bf16*)w;  w += (size_t)TT * EE * 2;
  bf16* ln1wB  = (bf16*)w;  w += (size_t)LL * EE * 2;
  bf16* ln1bB  = (bf16*)w;  w += (size_t)LL * EE * 2;
  bf16* ln2wB  = (bf16*)w;  w += (size_t)LL * EE * 2;
  bf16* ln2bB  = (bf16*)w;  w += (size_t)LL * EE * 2;
  bf16* attnbB = (bf16*)w;  w += (size_t)LL * E3 * 2;
  bf16* projbB = (bf16*)w;  w += (size_t)LL * EE * 2;
  bf16* fc1bB  = (bf16*)w;  w += (size_t)LL * E3 * 2;
  bf16* fc2bB  = (bf16*)w;  w += (size_t)LL * EE * 2;
  float2* part = (float2*)w; w += (size_t)BT * NBX * sizeof(float2);  // 2.0 MB LSE partials
  float* tgtv  = (float*)w;  w += (size_t)BT * 4;
  bf16* wteB   = (bf16*)w;  w += (size_t)VV * EE * 2;   // last: only used in mode A
  size_t need_a = (size_t)(w - (char*)d_ws);
  int modeA = ws_size >= need_a;

  bf16* out = (bf16*)d_out;
  const bf16* wte_use = modeA ? wteB : (const bf16*)wte_r;

  detect_kernel<<<1, 1, 0, stream>>>((const unsigned*)ln1w_r, flag, modeA ? 0 : 1);
  zero_loss_kernel<<<1, 1, 0, stream>>>(loss);

  // param conversions (copies when already bf16)
  if (modeA)
    convert_kernel<<<((size_t)VV * EE + 255) / 256, 256, 0, stream>>>(wte_r, wteB, (long)VV * EE, flag);
  convert_kernel<<<((size_t)TT * EE + 255) / 256, 256, 0, stream>>>(wpe_r, wpeB, (long)TT * EE, flag);
  convert_kernel<<<(LL * EE + 255) / 256, 256, 0, stream>>>(ln1w_r, ln1wB, LL * EE, flag);
  convert_kernel<<<(LL * EE + 255) / 256, 256, 0, stream>>>(ln1b_r, ln1bB, LL * EE, flag);
  convert_kernel<<<(LL * EE + 255) / 256, 256, 0, stream>>>(ln2w_r, ln2wB, LL * EE, flag);
  convert_kernel<<<(LL * EE + 255) / 256, 256, 0, stream>>>(ln2b_r, ln2bB, LL * EE, flag);
  convert_kernel<<<(LL * E3 + 255) / 256, 256, 0, stream>>>(attnb_r, attnbB, LL * E3, flag);
  convert_kernel<<<(LL * EE + 255) / 256, 256, 0, stream>>>(projb_r, projbB, LL * EE, flag);
  convert_kernel<<<(LL * E3 + 255) / 256, 256, 0, stream>>>(fc1b_r, fc1bB, LL * E3, flag);
  convert_kernel<<<(LL * EE + 255) / 256, 256, 0, stream>>>(fc2b_r, fc2bB, LL * EE, flag);

  const bf16* wpe_use = modeA ? wpeB : (const bf16*)wpe_r;

  for (int i = 0; i < LL; ++i) {
    // per-layer weight transposes (K x N -> N x K, bf16)
    transpose_kernel<<<dim3(E3/32, EE/32), dim3(32, 8), 0, stream>>>(attnw_r, aT, EE, E3, i, flag);
    transpose_kernel<<<dim3(EE/32, EE/32), dim3(32, 8), 0, stream>>>(projw_r, pT, EE, EE, i, flag);
    transpose_kernel<<<dim3(E3/32, EE/32), dim3(32, 8), 0, stream>>>(fc1w_r, f1T, EE, E3, i, flag);
    transpose_kernel<<<dim3(EE/32, E3/32), dim3(32, 8), 0, stream>>>(fc2w_r, f2T, E3, EE, i, flag);

    embed_kernel<<<BT, 256, 0, stream>>>(t[i], wte_use, wpe_use, x);
    ln_kernel<<<BT, 256, 0, stream>>>(x, ln1wB + i * EE, ln1bB + i * EE, h);
    gemm_bt<128, 128><<<dim3(E3/128, BT/128), 256, 0, stream>>>(
        h, aT, attnbB + i * E3, qkv, nullptr, nullptr, BT, E3, EE, 0);
    split_qkv_kernel<<<(BT * E3) / 256, 256, 0, stream>>>(qkv, Q, Km, Vt);
    attn_kernel<<<BB * HH * (TT / 16), 64, 0, stream>>>(Q, Km, Vt, y);
    gemm_bt<64, 64><<<dim3(EE/64, BT/64), 256, 0, stream>>>(
        y, pT, projbB + i * EE, nullptr, x, x, BT, EE, EE, 0);
    ln_kernel<<<BT, 256, 0, stream>>>(x, ln2wB + i * EE, ln2bB + i * EE, h);
    gemm_bt<128, 128><<<dim3(E3/128, BT/128), 256, 0, stream>>>(
        h, f1T, fc1bB + i * E3, g, nullptr, nullptr, BT, E3, EE, 1);
    gemm_bt<64, 64><<<dim3(EE/64, BT/64), 256, 0, stream>>>(
        g, f2T, fc2bB + i * EE, xb, x, x, BT, EE, E3, 0);
    // logits GEMM: 256x256 pipelined tile + fused partial-LSE; only final layer stores logits
    gemm256_logits<<<dim3(NBX, BT/256), 512, 0, stream>>>(
        xb, wte_use, (i == LL - 1) ? (void*)out : nullptr, flag, t[i + 1], part, tgtv);
    lse_reduce_kernel<<<BT, 256, 0, stream>>>(part, tgtv, loss, NBX);
  }
  write_loss_kernel<<<1, 1, 0, stream>>>(loss, (void*)d_out, flag);
}